// Round 2
// baseline (1105.914 us; speedup 1.0000x reference)
//
#include <hip/hip_runtime.h>
#include <hip/hip_bf16.h>

typedef __attribute__((ext_vector_type(8))) __bf16 bf16x8;
typedef __attribute__((ext_vector_type(4))) float f32x4;

#define NTOK 8192
#define D_DIM 1024
#define F_DIM 4096
#define NEXP 8
#define SLOT_TOT 16384          // 2 * NTOK
#define SLOT_CAP 16512          // SLOT_TOT + 128 padding

__device__ __forceinline__ unsigned short f2b(float f) {
  __hip_bfloat16 b = __float2bfloat16(f);
  return reinterpret_cast<unsigned short&>(b);
}

__device__ __forceinline__ void gload_lds16(const void* g, void* l) {
  __builtin_amdgcn_global_load_lds(
      (__attribute__((address_space(1))) void*)g,
      (__attribute__((address_space(3))) void*)l, 16, 0, 0);
}

// ---------------- small kernels ----------------

__global__ void init_counts_kernel(int* counts) {
  if (threadIdx.x < NEXP) counts[threadIdx.x] = 0;
}

__global__ void zero_out_kernel(float* out) {
  const int i = blockIdx.x * 256 + threadIdx.x;   // 8192*256 float4 = 8.4M floats
  reinterpret_cast<float4*>(out)[i] = make_float4(0.f, 0.f, 0.f, 0.f);
}

__global__ void convert_x_kernel(const float* __restrict__ x,
                                 __hip_bfloat16* __restrict__ xb) {
  const int i = (blockIdx.x * 256 + threadIdx.x) * 4;
  const float4 v = *reinterpret_cast<const float4*>(x + i);
  union { unsigned short u[4]; uint2 d; } o;
  o.u[0] = f2b(v.x); o.u[1] = f2b(v.y); o.u[2] = f2b(v.z); o.u[3] = f2b(v.w);
  *reinterpret_cast<uint2*>(xb + i) = o.d;
}

// src: per-expert [R][C] f32  ->  dst: per-expert [C][R] bf16
// 64x64 tile, 256 threads (16,16): float4 loads, uint2 (4x bf16) stores.
__global__ void transpose_conv_kernel(const float* __restrict__ src,
                                      __hip_bfloat16* __restrict__ dst,
                                      int R, int C) {
  __shared__ float tile[64][65];
  const int e = blockIdx.z;
  src += (size_t)e * R * C;
  dst += (size_t)e * R * C;
  const int c0 = blockIdx.x * 64, r0 = blockIdx.y * 64;
  const int tx = threadIdx.x, ty = threadIdx.y;   // (16, 16)
  #pragma unroll
  for (int j = 0; j < 4; ++j) {
    const float4 v = *reinterpret_cast<const float4*>(
        &src[(size_t)(r0 + ty + j * 16) * C + c0 + tx * 4]);
    tile[ty + j * 16][tx * 4 + 0] = v.x;
    tile[ty + j * 16][tx * 4 + 1] = v.y;
    tile[ty + j * 16][tx * 4 + 2] = v.z;
    tile[ty + j * 16][tx * 4 + 3] = v.w;
  }
  __syncthreads();
  #pragma unroll
  for (int j = 0; j < 4; ++j) {
    const int c = ty + j * 16;
    union { unsigned short u[4]; uint2 d; } o;
    #pragma unroll
    for (int i = 0; i < 4; ++i) o.u[i] = f2b(tile[tx * 4 + i][c]);
    *reinterpret_cast<uint2*>(&dst[(size_t)(c0 + c) * R + r0 + tx * 4]) = o.d;
  }
}

// ---------------- router ----------------
// one wave per token: logits = x[tok] . rw + rb ; top-2 ; renormalized softmax weights
__global__ void router_kernel(const float* __restrict__ x,
                              const float* __restrict__ rw,
                              const float* __restrict__ rb,
                              int* __restrict__ topk_idx,
                              float* __restrict__ topk_w,
                              int* __restrict__ counts) {
  __shared__ float rwT[NEXP * D_DIM];   // transposed [e][d], 32 KB
  const int tid = threadIdx.x;
  for (int i = tid; i < NEXP * D_DIM; i += 256) {
    const int d = i >> 3, e = i & 7;
    rwT[e * D_DIM + d] = rw[i];
  }
  __syncthreads();

  const int wave = tid >> 6, lane = tid & 63;
  const int tok = blockIdx.x * 4 + wave;
  const float* xr = x + (size_t)tok * D_DIM;

  float acc[NEXP];
  #pragma unroll
  for (int e = 0; e < NEXP; ++e) acc[e] = 0.f;

  for (int i = 0; i < D_DIM / 64; ++i) {
    const int d = i * 64 + lane;
    const float xv = xr[d];
    #pragma unroll
    for (int e = 0; e < NEXP; ++e) acc[e] += xv * rwT[e * D_DIM + d];
  }
  #pragma unroll
  for (int off = 32; off > 0; off >>= 1) {
    #pragma unroll
    for (int e = 0; e < NEXP; ++e) acc[e] += __shfl_xor(acc[e], off);
  }

  if (lane == 0) {
    float l[NEXP];
    #pragma unroll
    for (int e = 0; e < NEXP; ++e) l[e] = acc[e] + rb[e];
    int i1 = 0;
    #pragma unroll
    for (int e = 1; e < NEXP; ++e) if (l[e] > l[i1]) i1 = e;
    int i2 = (i1 == 0) ? 1 : 0;
    #pragma unroll
    for (int e = 0; e < NEXP; ++e) if (e != i1 && e != i2 && l[e] > l[i2]) i2 = e;
    const float w1 = 1.f / (1.f + __expf(l[i2] - l[i1]));
    topk_idx[tok * 2 + 0] = i1;
    topk_idx[tok * 2 + 1] = i2;
    topk_w[tok * 2 + 0] = w1;
    topk_w[tok * 2 + 1] = 1.f - w1;
    atomicAdd(&counts[i1], 1);
    atomicAdd(&counts[i2], 1);
  }
}

__global__ void offsets_kernel(const int* __restrict__ counts,
                               int* __restrict__ offsets,
                               int* __restrict__ cursors,
                               int* __restrict__ slot_token,
                               float* __restrict__ slot_cw) {
  const int t = threadIdx.x;
  if (t == 0) {
    int s = 0;
    for (int e = 0; e < NEXP; ++e) { offsets[e] = s; cursors[e] = s; s += counts[e]; }
    offsets[NEXP] = s;
  }
  if (t < SLOT_CAP - SLOT_TOT) {   // fill padding tail
    slot_token[SLOT_TOT + t] = 0;
    slot_cw[SLOT_TOT + t] = 0.f;
  }
}

__global__ void scatter_kernel(const int* __restrict__ topk_idx,
                               const float* __restrict__ topk_w,
                               int* __restrict__ cursors,
                               int* __restrict__ slot_token,
                               float* __restrict__ slot_cw) {
  const int tok = blockIdx.x * 256 + threadIdx.x;
  if (tok >= NTOK) return;
  #pragma unroll
  for (int k = 0; k < 2; ++k) {
    const int e = topk_idx[tok * 2 + k];
    const int p = atomicAdd(&cursors[e], 1);
    slot_token[p] = tok;
    slot_cw[p] = topk_w[tok * 2 + k];
  }
}

// ---------------- MFMA GEMMs ----------------
// 128x128 tile, BK=32, 4 waves (2x2 of 64x64), 16x16x32 bf16 MFMA.
// 2-phase double-buffered pipeline (T3-minimum): per K-step, issue next tile's
// global_load_lds BEFORE ds_read+MFMA of current tile; ONE __syncthreads()
// (vmcnt+lgkm drain + barrier) per K-step. LDS 2x(8+8) KB = 32 KB -> 5 blk/CU.
//
// Fragment-linear LDS: chunk (blk, wave-lane) at byte blk*1024 + lane*16 holds
//   A[blk*16 + (lane&15)][k0 + (lane>>4)*8 .. +8)   (B analogous with col)
// so global_load_lds (wave-uniform LDS base + lane*16) stages it directly and
// ds_read_b128 at lane*8 shorts is conflict-free.
template <int PHASE>
__global__ __launch_bounds__(256, 4) void moe_gemm(
    const __hip_bfloat16* __restrict__ A,
    const __hip_bfloat16* __restrict__ B,
    const float* __restrict__ bias,
    const int* __restrict__ slot_token,
    const float* __restrict__ slot_cw,
    const int* __restrict__ counts,
    const int* __restrict__ offsets,
    __hip_bfloat16* __restrict__ Hout,
    float* __restrict__ Out) {
  constexpr int K = (PHASE == 1) ? D_DIM : F_DIM;
  constexpr int NCOL = (PHASE == 1) ? F_DIM : D_DIM;
  constexpr int KT = K / 32;

  const int e = blockIdx.z;
  const int cnt = counts[e];
  const int mt = blockIdx.y;
  if (mt * 128 >= cnt) return;
  const int nt = blockIdx.x;
  const int base = offsets[e];

  __shared__ unsigned short lA[2][4096];   // 2 x 8 KB
  __shared__ unsigned short lB[2][4096];   // 2 x 8 KB

  const int tid = threadIdx.x;
  const int w = tid >> 6, lane = tid & 63;
  const int r = lane & 15, kg = lane >> 4;
  const int wm = w >> 1, wn = w & 1;

  // staging global pointers (two 16B loads each for A and B per K-step)
  const int rowA0 = mt * 128 + w * 16 + r;
  const int rowA1 = mt * 128 + (4 + w) * 16 + r;
  const __hip_bfloat16 *gA0, *gA1;
  if constexpr (PHASE == 1) {
    gA0 = A + (size_t)slot_token[base + rowA0] * K + kg * 8;
    gA1 = A + (size_t)slot_token[base + rowA1] * K + kg * 8;
  } else {
    gA0 = A + (size_t)(base + rowA0) * K + kg * 8;
    gA1 = A + (size_t)(base + rowA1) * K + kg * 8;
  }
  const __hip_bfloat16* Be = B + (size_t)e * NCOL * K;
  const __hip_bfloat16* gB0 = Be + (size_t)(nt * 128 + w * 16 + r) * K + kg * 8;
  const __hip_bfloat16* gB1 = Be + (size_t)(nt * 128 + (4 + w) * 16 + r) * K + kg * 8;

  f32x4 acc[4][4] = {};

#define STAGE(b) do {                       \
    gload_lds16(gA0, &lA[b][w * 512]);      \
    gload_lds16(gA1, &lA[b][(4 + w) * 512]);\
    gload_lds16(gB0, &lB[b][w * 512]);      \
    gload_lds16(gB1, &lB[b][(4 + w) * 512]);\
    gA0 += 32; gA1 += 32; gB0 += 32; gB1 += 32; } while (0)

#define COMPUTE(b) do {                                                     \
    bf16x8 af[4], bfr[4];                                                   \
    _Pragma("unroll") for (int i = 0; i < 4; ++i) {                         \
      af[i]  = *(const bf16x8*)&lA[b][(wm * 4 + i) * 512 + lane * 8];       \
      bfr[i] = *(const bf16x8*)&lB[b][(wn * 4 + i) * 512 + lane * 8];       \
    }                                                                       \
    _Pragma("unroll") for (int mi = 0; mi < 4; ++mi)                        \
      _Pragma("unroll") for (int ni = 0; ni < 4; ++ni)                      \
        acc[mi][ni] = __builtin_amdgcn_mfma_f32_16x16x32_bf16(             \
            af[mi], bfr[ni], acc[mi][ni], 0, 0, 0); } while (0)

  STAGE(0);
  __syncthreads();               // prologue: tile 0 resident
  int cur = 0;
  for (int kt = 0; kt < KT - 1; ++kt) {
    STAGE(cur ^ 1);              // issue next tile's loads (in flight across compute)
    COMPUTE(cur);                // ds_read + 16 MFMA on current tile
    __syncthreads();             // drain vmcnt/lgkm + barrier: next tile ready, cur free
    cur ^= 1;
  }
  COMPUTE(cur);                  // epilogue tile: no prefetch

#undef STAGE
#undef COMPUTE

  const int rem = cnt - mt * 128;
  const int q4 = (lane >> 4) * 4;

  if constexpr (PHASE == 1) {
    #pragma unroll
    for (int ni = 0; ni < 4; ++ni) {
      const int col = nt * 128 + wn * 64 + ni * 16 + (lane & 15);
      const float bv = bias[e * NCOL + col];
      #pragma unroll
      for (int mi = 0; mi < 4; ++mi) {
        #pragma unroll
        for (int rr = 0; rr < 4; ++rr) {
          const int rloc = wm * 64 + mi * 16 + q4 + rr;
          if (rloc < rem) {
            float v = acc[mi][ni][rr] + bv;
            v = 0.5f * v * (1.f + erff(v * 0.70710678118654752f));
            Hout[(size_t)(base + mt * 128 + rloc) * F_DIM + col] = __float2bfloat16(v);
          }
        }
      }
    }
  } else {
    #pragma unroll
    for (int mi = 0; mi < 4; ++mi) {
      int toks[4]; float cws[4];
      #pragma unroll
      for (int rr = 0; rr < 4; ++rr) {
        const int rloc = wm * 64 + mi * 16 + q4 + rr;
        const int slot = base + mt * 128 + rloc;
        const bool ok = (rloc < rem);
        toks[rr] = ok ? slot_token[slot] : -1;
        cws[rr]  = ok ? slot_cw[slot] : 0.f;
      }
      #pragma unroll
      for (int ni = 0; ni < 4; ++ni) {
        const int col = nt * 128 + wn * 64 + ni * 16 + (lane & 15);
        const float bv = bias[e * NCOL + col];
        #pragma unroll
        for (int rr = 0; rr < 4; ++rr) {
          if (toks[rr] >= 0)
            atomicAdd(&Out[(size_t)toks[rr] * D_DIM + col], cws[rr] * (acc[mi][ni][rr] + bv));
        }
      }
    }
  }
}

// ---------------- launch ----------------

extern "C" void kernel_launch(void* const* d_in, const int* in_sizes, int n_in,
                              void* d_out, int out_size, void* d_ws, size_t ws_size,
                              hipStream_t stream) {
  const float* x  = (const float*)d_in[0];
  const float* rw = (const float*)d_in[1];
  const float* rb = (const float*)d_in[2];
  const float* w1 = (const float*)d_in[3];
  const float* b1 = (const float*)d_in[4];
  const float* w2 = (const float*)d_in[5];
  const float* b2 = (const float*)d_in[6];
  float* out = (float*)d_out;

  char* p = (char*)d_ws;
  size_t used = 0;
  auto carve = [&](size_t bytes) {
    char* r = p + used;
    used += (bytes + 255) & ~(size_t)255;
    return (void*)r;
  };
  __hip_bfloat16* xb  = (__hip_bfloat16*)carve((size_t)NTOK * D_DIM * 2);
  __hip_bfloat16* w1t = (__hip_bfloat16*)carve((size_t)NEXP * F_DIM * D_DIM * 2);
  __hip_bfloat16* w2t = (__hip_bfloat16*)carve((size_t)NEXP * D_DIM * F_DIM * 2);
  __hip_bfloat16* h   = (__hip_bfloat16*)carve((size_t)SLOT_CAP * F_DIM * 2);
  int*   topk_idx   = (int*)carve((size_t)NTOK * 2 * 4);
  float* topk_w     = (float*)carve((size_t)NTOK * 2 * 4);
  int*   slot_token = (int*)carve((size_t)SLOT_CAP * 4);
  float* slot_cw    = (float*)carve((size_t)SLOT_CAP * 4);
  int* counts  = (int*)carve(256);
  int* offsets = (int*)carve(256);
  int* cursors = (int*)carve(256);

  // Workspace guard: leave output zeroed (diagnosable absmax ~= 1.99) if ws too small.
  zero_out_kernel<<<8192, 256, 0, stream>>>(out);
  if (used > ws_size) return;

  init_counts_kernel<<<1, 64, 0, stream>>>(counts);
  router_kernel<<<NTOK / 4, 256, 0, stream>>>(x, rw, rb, topk_idx, topk_w, counts);
  offsets_kernel<<<1, 256, 0, stream>>>(counts, offsets, cursors, slot_token, slot_cw);
  scatter_kernel<<<NTOK / 256, 256, 0, stream>>>(topk_idx, topk_w, cursors, slot_token, slot_cw);

  convert_x_kernel<<<(NTOK * D_DIM) / (256 * 4), 256, 0, stream>>>(x, xb);
  dim3 tb(16, 16);
  transpose_conv_kernel<<<dim3(F_DIM / 64, D_DIM / 64, NEXP), tb, 0, stream>>>(w1, w1t, D_DIM, F_DIM);
  transpose_conv_kernel<<<dim3(D_DIM / 64, F_DIM / 64, NEXP), tb, 0, stream>>>(w2, w2t, F_DIM, D_DIM);

  moe_gemm<1><<<dim3(F_DIM / 128, 64, NEXP), 256, 0, stream>>>(
      xb, w1t, b1, slot_token, slot_cw, counts, offsets, h, nullptr);
  moe_gemm<2><<<dim3(D_DIM / 128, 64, NEXP), 256, 0, stream>>>(
      h, w2t, b2, slot_token, slot_cw, counts, offsets, nullptr, out);
}

// Round 3
// 1069.542 us; speedup vs baseline: 1.0340x; 1.0340x over previous
//
#include <hip/hip_runtime.h>
#include <hip/hip_bf16.h>

typedef __attribute__((ext_vector_type(8))) __bf16 bf16x8;
typedef __attribute__((ext_vector_type(4))) float f32x4;

#define NTOK 8192
#define D_DIM 1024
#define F_DIM 4096
#define NEXP 8
#define SLOT_TOT 16384          // 2 * NTOK
#define SLOT_CAP 16640          // SLOT_TOT + 256 padding (BM=256 tail)

__device__ __forceinline__ unsigned short f2b(float f) {
  __hip_bfloat16 b = __float2bfloat16(f);
  return reinterpret_cast<unsigned short&>(b);
}

__device__ __forceinline__ void gload_lds16(const void* g, void* l) {
  __builtin_amdgcn_global_load_lds(
      (__attribute__((address_space(1))) void*)g,
      (__attribute__((address_space(3))) void*)l, 16, 0, 0);
}

// ---------------- small kernels ----------------

__global__ void init_counts_kernel(int* counts) {
  if (threadIdx.x < NEXP) counts[threadIdx.x] = 0;
}

__global__ void zero_out_kernel(float* out) {
  const int i = blockIdx.x * 256 + threadIdx.x;   // 8192*256 float4 = 8.4M floats
  reinterpret_cast<float4*>(out)[i] = make_float4(0.f, 0.f, 0.f, 0.f);
}

__global__ void convert_x_kernel(const float* __restrict__ x,
                                 __hip_bfloat16* __restrict__ xb) {
  const int i = (blockIdx.x * 256 + threadIdx.x) * 4;
  const float4 v = *reinterpret_cast<const float4*>(x + i);
  union { unsigned short u[4]; uint2 d; } o;
  o.u[0] = f2b(v.x); o.u[1] = f2b(v.y); o.u[2] = f2b(v.z); o.u[3] = f2b(v.w);
  *reinterpret_cast<uint2*>(xb + i) = o.d;
}

// src: per-expert [R][C] f32  ->  dst: per-expert [C][R] bf16
// 64x64 tile, 256 threads (16,16): float4 loads, uint2 (4x bf16) stores.
__global__ void transpose_conv_kernel(const float* __restrict__ src,
                                      __hip_bfloat16* __restrict__ dst,
                                      int R, int C) {
  __shared__ float tile[64][65];
  const int e = blockIdx.z;
  src += (size_t)e * R * C;
  dst += (size_t)e * R * C;
  const int c0 = blockIdx.x * 64, r0 = blockIdx.y * 64;
  const int tx = threadIdx.x, ty = threadIdx.y;   // (16, 16)
  #pragma unroll
  for (int j = 0; j < 4; ++j) {
    const float4 v = *reinterpret_cast<const float4*>(
        &src[(size_t)(r0 + ty + j * 16) * C + c0 + tx * 4]);
    tile[ty + j * 16][tx * 4 + 0] = v.x;
    tile[ty + j * 16][tx * 4 + 1] = v.y;
    tile[ty + j * 16][tx * 4 + 2] = v.z;
    tile[ty + j * 16][tx * 4 + 3] = v.w;
  }
  __syncthreads();
  #pragma unroll
  for (int j = 0; j < 4; ++j) {
    const int c = ty + j * 16;
    union { unsigned short u[4]; uint2 d; } o;
    #pragma unroll
    for (int i = 0; i < 4; ++i) o.u[i] = f2b(tile[tx * 4 + i][c]);
    *reinterpret_cast<uint2*>(&dst[(size_t)(c0 + c) * R + r0 + tx * 4]) = o.d;
  }
}

// ---------------- router ----------------
__global__ void router_kernel(const float* __restrict__ x,
                              const float* __restrict__ rw,
                              const float* __restrict__ rb,
                              int* __restrict__ topk_idx,
                              float* __restrict__ topk_w,
                              int* __restrict__ counts) {
  __shared__ float rwT[NEXP * D_DIM];   // transposed [e][d], 32 KB
  const int tid = threadIdx.x;
  for (int i = tid; i < NEXP * D_DIM; i += 256) {
    const int d = i >> 3, e = i & 7;
    rwT[e * D_DIM + d] = rw[i];
  }
  __syncthreads();

  const int wave = tid >> 6, lane = tid & 63;
  const int tok = blockIdx.x * 4 + wave;
  const float* xr = x + (size_t)tok * D_DIM;

  float acc[NEXP];
  #pragma unroll
  for (int e = 0; e < NEXP; ++e) acc[e] = 0.f;

  for (int i = 0; i < D_DIM / 64; ++i) {
    const int d = i * 64 + lane;
    const float xv = xr[d];
    #pragma unroll
    for (int e = 0; e < NEXP; ++e) acc[e] += xv * rwT[e * D_DIM + d];
  }
  #pragma unroll
  for (int off = 32; off > 0; off >>= 1) {
    #pragma unroll
    for (int e = 0; e < NEXP; ++e) acc[e] += __shfl_xor(acc[e], off);
  }

  if (lane == 0) {
    float l[NEXP];
    #pragma unroll
    for (int e = 0; e < NEXP; ++e) l[e] = acc[e] + rb[e];
    int i1 = 0;
    #pragma unroll
    for (int e = 1; e < NEXP; ++e) if (l[e] > l[i1]) i1 = e;
    int i2 = (i1 == 0) ? 1 : 0;
    #pragma unroll
    for (int e = 0; e < NEXP; ++e) if (e != i1 && e != i2 && l[e] > l[i2]) i2 = e;
    const float w1 = 1.f / (1.f + __expf(l[i2] - l[i1]));
    topk_idx[tok * 2 + 0] = i1;
    topk_idx[tok * 2 + 1] = i2;
    topk_w[tok * 2 + 0] = w1;
    topk_w[tok * 2 + 1] = 1.f - w1;
    atomicAdd(&counts[i1], 1);
    atomicAdd(&counts[i2], 1);
  }
}

__global__ void offsets_kernel(const int* __restrict__ counts,
                               int* __restrict__ offsets,
                               int* __restrict__ cursors,
                               int* __restrict__ slot_token,
                               float* __restrict__ slot_cw) {
  const int t = threadIdx.x;
  if (t == 0) {
    int s = 0;
    for (int e = 0; e < NEXP; ++e) { offsets[e] = s; cursors[e] = s; s += counts[e]; }
    offsets[NEXP] = s;
  }
  if (t < SLOT_CAP - SLOT_TOT) {   // fill padding tail (256 entries)
    slot_token[SLOT_TOT + t] = 0;
    slot_cw[SLOT_TOT + t] = 0.f;
  }
}

__global__ void scatter_kernel(const int* __restrict__ topk_idx,
                               const float* __restrict__ topk_w,
                               int* __restrict__ cursors,
                               int* __restrict__ slot_token,
                               float* __restrict__ slot_cw) {
  const int tok = blockIdx.x * 256 + threadIdx.x;
  if (tok >= NTOK) return;
  #pragma unroll
  for (int k = 0; k < 2; ++k) {
    const int e = topk_idx[tok * 2 + k];
    const int p = atomicAdd(&cursors[e], 1);
    slot_token[p] = tok;
    slot_cw[p] = topk_w[tok * 2 + k];
  }
}

// ---------------- MFMA GEMMs ----------------
// 256x128 tile, BK=32, 512 threads = 8 waves (4M x 2N), per-wave 64x64 output.
// Ring-3 LDS pipeline with counted vmcnt (T4): prologue stages 3 K-tiles
// (9 global_load_lds per wave in flight); each iteration:
//   s_waitcnt vmcnt(6)   <- oldest tile's 3 loads retired (in-order), NEVER 0
//   s_barrier            <- all waves' tile-t loads landed
//   compute(t)           <- 8 ds_read_b128 + 16 MFMA (compiler inserts lgkm waits)
//   s_barrier            <- all waves done reading buf (safe to overwrite)
//   stage(t+3)           <- 3 loads, back to 9 outstanding
// Fragment-linear LDS (conflict-free, measured 0 conflicts): chunk g (1 KB) at
// g*1024 B holds rows g*16+(lane&15), k = (lane>>4)*8..+8 as lane*16 bytes.
template <int PHASE>
__global__ __launch_bounds__(512, 4) void moe_gemm(
    const __hip_bfloat16* __restrict__ A,
    const __hip_bfloat16* __restrict__ B,
    const float* __restrict__ bias,
    const int* __restrict__ slot_token,
    const float* __restrict__ slot_cw,
    const int* __restrict__ counts,
    const int* __restrict__ offsets,
    __hip_bfloat16* __restrict__ Hout,
    float* __restrict__ Out) {
  constexpr int K = (PHASE == 1) ? D_DIM : F_DIM;
  constexpr int NCOL = (PHASE == 1) ? F_DIM : D_DIM;
  constexpr int KT = K / 32;

  const int e = blockIdx.z;
  const int cnt = counts[e];
  const int mt = blockIdx.y;
  if (mt * 256 >= cnt) return;
  const int nt = blockIdx.x;
  const int base = offsets[e];

  __shared__ unsigned short lA[3][8192];   // 3 x 16 KB (16 chunks each)
  __shared__ unsigned short lB[3][4096];   // 3 x  8 KB ( 8 chunks each)

  const int tid = threadIdx.x;
  const int w = tid >> 6, lane = tid & 63;
  const int r = lane & 15, kg = lane >> 4;
  const int wm = w >> 1, wn = w & 1;

  // staging pointers: wave w stages A row-groups {w, w+8} and B col-group {w}
  const int rowA0 = mt * 256 + w * 16 + r;
  const int rowA1 = mt * 256 + (w + 8) * 16 + r;
  const __hip_bfloat16 *gA0, *gA1;
  if constexpr (PHASE == 1) {
    gA0 = A + (size_t)slot_token[base + rowA0] * K + kg * 8;
    gA1 = A + (size_t)slot_token[base + rowA1] * K + kg * 8;
  } else {
    gA0 = A + (size_t)(base + rowA0) * K + kg * 8;
    gA1 = A + (size_t)(base + rowA1) * K + kg * 8;
  }
  const __hip_bfloat16* Be = B + (size_t)e * NCOL * K;
  const __hip_bfloat16* gB0 = Be + (size_t)(nt * 128 + w * 16 + r) * K + kg * 8;

  f32x4 acc[4][4] = {};

  auto stage = [&](unsigned short* pa, unsigned short* pb) {
    gload_lds16(gA0, pa + w * 512);
    gload_lds16(gA1, pa + (w + 8) * 512);
    gload_lds16(gB0, pb + w * 512);
    gA0 += 32; gA1 += 32; gB0 += 32;
  };
  auto compute = [&](const unsigned short* pa, const unsigned short* pb) {
    bf16x8 af[4], bfr[4];
    #pragma unroll
    for (int i = 0; i < 4; ++i) {
      af[i]  = *(const bf16x8*)(pa + (wm * 4 + i) * 512 + lane * 8);
      bfr[i] = *(const bf16x8*)(pb + (wn * 4 + i) * 512 + lane * 8);
    }
    #pragma unroll
    for (int mi = 0; mi < 4; ++mi)
      #pragma unroll
      for (int ni = 0; ni < 4; ++ni)
        acc[mi][ni] = __builtin_amdgcn_mfma_f32_16x16x32_bf16(
            af[mi], bfr[ni], acc[mi][ni], 0, 0, 0);
  };

  unsigned short *pa0 = lA[0], *pa1 = lA[1], *pa2 = lA[2];
  unsigned short *pb0 = lB[0], *pb1 = lB[1], *pb2 = lB[2];

  stage(pa0, pb0);
  stage(pa1, pb1);
  stage(pa2, pb2);    // 9 loads outstanding per wave

  for (int t = 0; t < KT - 3; ++t) {
    asm volatile("s_waitcnt vmcnt(6)" ::: "memory");
    __builtin_amdgcn_sched_barrier(0);
    __builtin_amdgcn_s_barrier();
    __builtin_amdgcn_sched_barrier(0);
    compute(pa0, pb0);
    __builtin_amdgcn_sched_barrier(0);
    __builtin_amdgcn_s_barrier();
    __builtin_amdgcn_sched_barrier(0);
    stage(pa0, pb0);                       // overwrite: tile t+3
    unsigned short* ta = pa0; pa0 = pa1; pa1 = pa2; pa2 = ta;
    unsigned short* tb = pb0; pb0 = pb1; pb1 = pb2; pb2 = tb;
  }
  // t = KT-3: 9 outstanding -> wait 6
  asm volatile("s_waitcnt vmcnt(6)" ::: "memory");
  __builtin_amdgcn_sched_barrier(0);
  __builtin_amdgcn_s_barrier();
  __builtin_amdgcn_sched_barrier(0);
  compute(pa0, pb0);
  // t = KT-2: 6 outstanding -> wait 3
  asm volatile("s_waitcnt vmcnt(3)" ::: "memory");
  __builtin_amdgcn_sched_barrier(0);
  __builtin_amdgcn_s_barrier();
  __builtin_amdgcn_sched_barrier(0);
  compute(pa1, pb1);
  // t = KT-1: 3 outstanding -> wait 0
  asm volatile("s_waitcnt vmcnt(0)" ::: "memory");
  __builtin_amdgcn_sched_barrier(0);
  __builtin_amdgcn_s_barrier();
  __builtin_amdgcn_sched_barrier(0);
  compute(pa2, pb2);

  const int rem = cnt - mt * 256;
  const int q4 = (lane >> 4) * 4;

  if constexpr (PHASE == 1) {
    #pragma unroll
    for (int ni = 0; ni < 4; ++ni) {
      const int col = nt * 128 + wn * 64 + ni * 16 + (lane & 15);
      const float bv = bias[e * NCOL + col];
      #pragma unroll
      for (int mi = 0; mi < 4; ++mi) {
        #pragma unroll
        for (int rr = 0; rr < 4; ++rr) {
          const int rloc = wm * 64 + mi * 16 + q4 + rr;
          if (rloc < rem) {
            float v = acc[mi][ni][rr] + bv;
            v = 0.5f * v * (1.f + erff(v * 0.70710678118654752f));
            Hout[(size_t)(base + mt * 256 + rloc) * F_DIM + col] = __float2bfloat16(v);
          }
        }
      }
    }
  } else {
    #pragma unroll
    for (int mi = 0; mi < 4; ++mi) {
      int toks[4]; float cws[4];
      #pragma unroll
      for (int rr = 0; rr < 4; ++rr) {
        const int rloc = wm * 64 + mi * 16 + q4 + rr;
        const int slot = base + mt * 256 + rloc;
        const bool ok = (rloc < rem);
        toks[rr] = ok ? slot_token[slot] : -1;
        cws[rr]  = ok ? slot_cw[slot] : 0.f;
      }
      #pragma unroll
      for (int ni = 0; ni < 4; ++ni) {
        const int col = nt * 128 + wn * 64 + ni * 16 + (lane & 15);
        const float bv = bias[e * NCOL + col];
        #pragma unroll
        for (int rr = 0; rr < 4; ++rr) {
          if (toks[rr] >= 0)
            atomicAdd(&Out[(size_t)toks[rr] * D_DIM + col], cws[rr] * (acc[mi][ni][rr] + bv));
        }
      }
    }
  }
}

// ---------------- launch ----------------

extern "C" void kernel_launch(void* const* d_in, const int* in_sizes, int n_in,
                              void* d_out, int out_size, void* d_ws, size_t ws_size,
                              hipStream_t stream) {
  const float* x  = (const float*)d_in[0];
  const float* rw = (const float*)d_in[1];
  const float* rb = (const float*)d_in[2];
  const float* w1 = (const float*)d_in[3];
  const float* b1 = (const float*)d_in[4];
  const float* w2 = (const float*)d_in[5];
  const float* b2 = (const float*)d_in[6];
  float* out = (float*)d_out;

  char* p = (char*)d_ws;
  size_t used = 0;
  auto carve = [&](size_t bytes) {
    char* r = p + used;
    used += (bytes + 255) & ~(size_t)255;
    return (void*)r;
  };
  __hip_bfloat16* xb  = (__hip_bfloat16*)carve((size_t)NTOK * D_DIM * 2);
  __hip_bfloat16* w1t = (__hip_bfloat16*)carve((size_t)NEXP * F_DIM * D_DIM * 2);
  __hip_bfloat16* w2t = (__hip_bfloat16*)carve((size_t)NEXP * D_DIM * F_DIM * 2);
  __hip_bfloat16* h   = (__hip_bfloat16*)carve((size_t)SLOT_CAP * F_DIM * 2);
  int*   topk_idx   = (int*)carve((size_t)NTOK * 2 * 4);
  float* topk_w     = (float*)carve((size_t)NTOK * 2 * 4);
  int*   slot_token = (int*)carve((size_t)SLOT_CAP * 4);
  float* slot_cw    = (float*)carve((size_t)SLOT_CAP * 4);
  int* counts  = (int*)carve(256);
  int* offsets = (int*)carve(256);
  int* cursors = (int*)carve(256);

  // Workspace guard: leave output zeroed (diagnosable absmax ~= 1.99) if ws too small.
  zero_out_kernel<<<8192, 256, 0, stream>>>(out);
  if (used > ws_size) return;

  init_counts_kernel<<<1, 64, 0, stream>>>(counts);
  router_kernel<<<NTOK / 4, 256, 0, stream>>>(x, rw, rb, topk_idx, topk_w, counts);
  offsets_kernel<<<1, 256, 0, stream>>>(counts, offsets, cursors, slot_token, slot_cw);
  scatter_kernel<<<NTOK / 256, 256, 0, stream>>>(topk_idx, topk_w, cursors, slot_token, slot_cw);

  convert_x_kernel<<<(NTOK * D_DIM) / (256 * 4), 256, 0, stream>>>(x, xb);
  dim3 tb(16, 16);
  transpose_conv_kernel<<<dim3(F_DIM / 64, D_DIM / 64, NEXP), tb, 0, stream>>>(w1, w1t, D_DIM, F_DIM);
  transpose_conv_kernel<<<dim3(D_DIM / 64, F_DIM / 64, NEXP), tb, 0, stream>>>(w2, w2t, F_DIM, D_DIM);

  // BM=256: y = 8192/256 = 32 covers worst-case per-expert count
  moe_gemm<1><<<dim3(F_DIM / 128, 32, NEXP), 512, 0, stream>>>(
      xb, w1t, b1, slot_token, slot_cw, counts, offsets, h, nullptr);
  moe_gemm<2><<<dim3(D_DIM / 128, 32, NEXP), 512, 0, stream>>>(
      h, w2t, b2, slot_token, slot_cw, counts, offsets, nullptr, out);
}